// Round 5
// baseline (579.720 us; speedup 1.0000x reference)
//
#include <hip/hip_runtime.h>
#include <math.h>
#include <string.h>

typedef unsigned short ushort_t;
typedef __attribute__((ext_vector_type(8))) short bhalf8;
typedef __attribute__((ext_vector_type(4))) float floatx4;

// Problem constants
#define NN    8
#define CC_   96
#define HH    56
#define WW    56
#define HWHW  (HH*WW)            // 3136
#define NPIX  (NN*HWHW)          // 25088
#define NELEM (NN*CC_*HWHW)      // 2408448
#define GROUPS 4
#define IG    24                 // channels per group
#define NITER 25
#define EPSV  1e-12f
#define TS    40                 // LDS ch-slot stride (ushorts) = 80 B

// bf16 helpers (RNE)
__device__ __forceinline__ unsigned bf2pack(float a, float b) {
    unsigned ua = __float_as_uint(a), ub = __float_as_uint(b);
    ua += 0x7fffu + ((ua >> 16) & 1u);
    ub += 0x7fffu + ((ub >> 16) & 1u);
    return (ua >> 16) | (ub & 0xffff0000u);
}
__device__ __forceinline__ ushort_t bf1pack(float a) {
    unsigned ua = __float_as_uint(a);
    ua += 0x7fffu + ((ua >> 16) & 1u);
    return (ushort_t)(ua >> 16);
}
__device__ __forceinline__ float bflo(unsigned u) { return __uint_as_float(u << 16); }
__device__ __forceinline__ float bfhi(unsigned u) { return __uint_as_float(u & 0xffff0000u); }

// fast reciprocal: v_rcp_f32 (~1 ulp), error far below bf16 pack rounding
__device__ __forceinline__ float rcpf(float x) {
    float r;
    asm("v_rcp_f32 %0, %1" : "=v"(r) : "v"(x));
    return r;
}

// LDS chunk-XOR swizzle: slot stride TS=40 ushorts (80B); data = 4 chunks of
// 16B (u = 0..31). chunk' = chunk ^ ((slot>>3)&3) makes the lanes nn / nn+8
// (slot delta 8) map to disjoint 4-bank sets on ds_read_b128. Bijective per
// slot; all accesses stay within one 16B chunk, so writes/reads stay paired.
__device__ __forceinline__ int swz(int slot, int u) {
    return slot*TS + ((((u >> 3) ^ (slot >> 3)) & 3) << 3) + (u & 7);
}

// ---------------------------------------------------------------------------
// Normalize weights -> Wn[96][216] fp32
__global__ void wnorm_n_kernel(const float* __restrict__ w_in, float* __restrict__ Wn) {
    int o = blockIdx.x;
    int t = threadIdx.x;
    float myv = (t < 216) ? fabsf(w_in[o*216 + t]) : 0.f;
    float v = myv;
    #pragma unroll
    for (int off = 32; off; off >>= 1) v += __shfl_down(v, off, 64);
    __shared__ float red[4];
    if ((t & 63) == 0) red[t >> 6] = v;
    __syncthreads();
    float s = red[0] + red[1] + red[2] + red[3];
    if (t < 216) Wn[o*216 + t] = myv / (s + EPSV);
}

// ---------------------------------------------------------------------------
// Pack conv A-fragments (bf16) for MFMA 16x16x32 (verified round 7/9).
__global__ void wpack_kernel(const float* __restrict__ Wn,
                             ushort_t* __restrict__ WfP, ushort_t* __restrict__ WtP) {
    int bi = blockIdx.x;             // 144 = 2 sel * 72
    int sel = bi / 72;
    int rem = bi % 72;
    int ot = rem & 1;
    int gt = rem >> 1;               // g*9 + tap
    int g = gt / 9, tap = gt % 9;
    int lane = threadIdx.x;
    int quad = lane >> 4, nn = lane & 15;
    int m = ot*16 + nn;
    ushort_t v[8];
    #pragma unroll
    for (int j = 0; j < 8; ++j) {
        int kc = quad*8 + j;
        float val = 0.f;
        if (m < IG && kc < IG) {
            if (sel == 0) val = Wn[(g*IG + m)*216 + kc*9 + tap];
            else          val = Wn[(g*IG + kc)*216 + m*9 + (8 - tap)];
        }
        v[j] = bf1pack(val);
    }
    ushort_t* dst = (sel ? WtP : WfP) + ((size_t)(gt*2 + ot)*64 + lane)*8;
    *(uint4*)dst = *(uint4*)v;
}

// ---------------------------------------------------------------------------
// Pack MLP weight fragments (verified round 9).
__global__ void mlppack_kernel(const float* __restrict__ w1, const float* __restrict__ w2,
                               ushort_t* __restrict__ w1P, ushort_t* __restrict__ w2P) {
    int f = blockIdx.x;              // 144: 72 for w1 (24nt*3ks), 72 for w2 (6mt*12ks)
    int lane = threadIdx.x;
    int quad = lane >> 4, nn = lane & 15;
    ushort_t v[8];
    if (f < 72) {
        int nt = f / 3, ks = f % 3;
        #pragma unroll
        for (int j = 0; j < 8; ++j)
            v[j] = bf1pack(w1[(size_t)(ks*32 + quad*8 + j)*384 + nt*16 + nn]);
        *(uint4*)(w1P + ((size_t)f*64 + lane)*8) = *(uint4*)v;
    } else {
        int f2 = f - 72;
        int mt = f2 / 12, ks = f2 % 12;
        #pragma unroll
        for (int j = 0; j < 8; ++j)
            v[j] = bf1pack(w2[(size_t)(ks*32 + quad*8 + j)*96 + mt*16 + nn]);
        *(uint4*)(w2P + ((size_t)f2*64 + lane)*8) = *(uint4*)v;
    }
}

// ---------------------------------------------------------------------------
// LN1 -> relu -> channel-normalize => Xp (bf16 channel-pairs).
__global__ void ln1_kernel(const float* __restrict__ x, const float* __restrict__ lw,
                           const float* __restrict__ lb, unsigned* __restrict__ Xp) {
    int p = blockIdx.x * blockDim.x + threadIdx.x;
    if (p >= NPIX) return;
    int n = p / HWHW, hw = p % HWHW;
    const float* xp = x + (size_t)n*CC_*HWHW + hw;
    float s = 0.f, ss = 0.f;
    for (int c = 0; c < CC_; ++c) { float v = xp[(size_t)c*HWHW]; s += v; ss += v*v; }
    float u  = s * (1.f/CC_);
    float var = ss * (1.f/CC_) - u*u;
    float rs = rsqrtf(var + 1e-6f);
    float sr = 0.f;
    for (int c = 0; c < CC_; ++c) {
        float v = xp[(size_t)c*HWHW];
        float a = fmaxf((v-u)*rs*lw[c] + lb[c], 0.f);
        sr += a;
    }
    float inv = 1.f / (sr + EPSV);
    for (int c = 0; c < CC_; c += 2) {
        float v0 = xp[(size_t)c*HWHW];
        float v1 = xp[(size_t)(c+1)*HWHW];
        float a0 = fmaxf((v0-u)*rs*lw[c] + lb[c], 0.f) * inv;
        float a1 = fmaxf((v1-u)*rs*lw[c+1] + lb[c+1], 0.f) * inv;
        int g = c / IG, pr = (c % IG) >> 1;
        Xp[(size_t)((n*4+g)*12 + pr)*HWHW + hw] = bf2pack(a0, a1);
    }
}

// ---------------------------------------------------------------------------
// Fused NNMF iteration (MFMA), 4-row band tile, 25 launches (1 per iteration).
// Round 13: occupancy-first. 896 blocks, LDS 37.8KB, ot-SPLIT phases keep
// VGPR <= 64 => __launch_bounds__(512,8) => 4 blocks/CU = 32 waves/CU.
// Latency-bound theory: double TLP beats halved LDS traffic (round-4 null).
// XCD-locality: all 28 tiles of an (n,g) group land on one XCD.
// it0: staging from constants (fills eliminated); bit-exact vs filled path.
__global__ __launch_bounds__(512, 8) void nnmf_mfma_kernel(
        const unsigned* __restrict__ HupI, unsigned* __restrict__ HupO,
        const float* __restrict__ Scur, float* __restrict__ Snxt,
        const ushort_t* __restrict__ WtP, const ushort_t* __restrict__ WfP,
        const unsigned* __restrict__ Xp,
        int it0, unsigned huInit, float sInit) {
    __shared__ ushort_t hn[256*TS];      // HuN tile [row8*32+pos][40]  20480 B
    __shared__ ushort_t rt_[192*TS];     // R   tile [row6*32+pos][40]  15360 B
    __shared__ float sinv[256];
    __shared__ float sacc[224];
    int b    = blockIdx.x;               // 896
    // XCD-aware decode: xcd = b&7, 4 ng-groups x 28 tiles per XCD
    int k_   = b >> 3;                   // 0..111
    int ng   = (b & 7)*4 + k_/28;        // 0..31
    int tile = k_ % 28;                  // 0..27
    int rtb  = tile >> 1;                // 0..13
    int half = tile & 1;
    int n    = ng >> 2;
    int g    = ng & 3;
    int tid  = threadIdx.x;
    int r0   = rtb*4;
    int xb   = half*28;
    unsigned planeBase = (unsigned)(n*4 + g)*12;

    int waveId = tid >> 6, lane = tid & 63;
    int quad = lane >> 4, nn = lane & 15;
    int otB = waveId & 1;
    int mbB = otB*16 + quad*4;           // phase-B output channel base

    // convT weight frags early (ot-split: 9 frags, 36 VGPR)
    bhalf8 afrB[9];
    {
        const ushort_t* ap = WtP + ((size_t)(g*9*2 + otB)*64 + lane)*8;
        #pragma unroll
        for (int t = 0; t < 9; ++t) afrB[t] = *(const bhalf8*)(ap + (size_t)t*2*64*8);
    }

    // ---- sinv for the 8x32 staging grid (gr = r0-2+r, gc = xb-2+q)
    if (tid < 256) {
        int r = tid >> 5, q = tid & 31;
        int gr = r0 - 2 + r, gc = xb - 2 + q;
        float st = 1.f;
        if (gr >= 0 && gr < HH && gc >= 0 && gc < WW) {
            if (it0) {
                st = 4.f*sInit;          // == sum of 4 filled planes, exact
            } else {
                unsigned p = (unsigned)(n*HWHW + gr*WW + gc);
                st = Scur[p] + Scur[NPIX+p] + Scur[2*NPIX+p] + Scur[3*NPIX+p];
            }
        }
        sinv[tid] = rcpf(st + EPSV);
    }
    __syncthreads();

    // ---- stage HuN (bf16 in -> *si -> bf16); pr2 6,7 zero the K-pad chunks
    #pragma unroll
    for (int kk = 0; kk < 4; ++kk) {
        int idx  = tid + kk*512;         // 0..2047
        int pr2  = idx >> 8;             // 0..7 (6 used)
        int slot = idx & 255;
        int r = slot >> 5, q = slot & 31;
        int gr = r0 - 2 + r, gc = xb - 2 + q;
        uint2 pk = {0u, 0u};
        if (pr2 < 6 && gr >= 0 && gr < HH && gc >= 0 && gc < WW) {
            float si = sinv[slot];
            if (it0) {
                float hval = bflo(huInit) * si;
                pk.x = bf2pack(hval, hval);
                pk.y = pk.x;
            } else {
                unsigned off = (unsigned)(gr*WW + gc);
                unsigned a = HupI[(size_t)(planeBase + 2*pr2)*HWHW + off];
                unsigned c = HupI[(size_t)(planeBase + 2*pr2 + 1)*HWHW + off];
                pk.x = bf2pack(bflo(a)*si, bfhi(a)*si);
                pk.y = bf2pack(bflo(c)*si, bfhi(c)*si);
            }
        }
        *(uint2*)&hn[swz(slot, 4*pr2)] = pk;
    }
    if (tid < 192) *(uint4*)&rt_[swz(tid, 24)] = (uint4){0u,0u,0u,0u};
    __syncthreads();

    // ---- Phase B: convT -> R band (6 rows x 30 px) in LDS; 3 tasks/wave
    {
        #pragma unroll
        for (int i = 0; i < 3; ++i) {
            int tk  = waveId + 8*i;      // 0..23, ot = tk&1 == otB
            int pt  = (tk >> 1) & 1;
            int row = tk >> 2;           // 0..5 (gr = r0-1+row)
            int x0R = pt*14;
            // hoisted ratio operands
            unsigned xa = 0u, xc = 0u;
            int gr = r0 - 1 + row, gc = xb - 1 + x0R + nn;
            if (mbB < IG && gr >= 0 && gr < HH && gc >= 0 && gc < WW) {
                unsigned off = (unsigned)(gr*WW + gc);
                unsigned pb = planeBase + (unsigned)(mbB >> 1);
                xa = Xp[(size_t)pb*HWHW + off];
                xc = Xp[(size_t)(pb+1)*HWHW + off];
            }
            floatx4 acc = (floatx4){0.f,0.f,0.f,0.f};
            #pragma unroll
            for (int t = 0; t < 9; ++t) {
                int ky = t / 3, kx = t % 3;
                bhalf8 bfr = *(const bhalf8*)
                    &hn[swz((row + ky)*32 + kx + nn + x0R, quad*8)];
                acc = __builtin_amdgcn_mfma_f32_16x16x32_bf16(afrB[t], bfr, acc, 0, 0, 0);
            }
            if (mbB < IG) {
                int slot = row*32 + x0R + nn;
                *(unsigned*)&rt_[swz(slot, mbB)] =
                    bf2pack(bflo(xa)*rcpf(acc[0]+EPSV), bfhi(xa)*rcpf(acc[1]+EPSV));
                *(unsigned*)&rt_[swz(slot, mbB + 2)] =
                    bf2pack(bflo(xc)*rcpf(acc[2]+EPSV), bfhi(xc)*rcpf(acc[3]+EPSV));
            }
        }
    }
    __syncthreads();

    // ---- Phase C: forward conv + multiplicative update (Hu from LDS)
    {
        int w  = waveId & 3;             // out row in band
        int ot = waveId >> 2;
        const ushort_t* ap = WfP + ((size_t)(g*9*2 + ot)*64 + lane)*8;
        bhalf8 afr[9];
        #pragma unroll
        for (int t = 0; t < 9; ++t) afr[t] = *(const bhalf8*)(ap + (size_t)t*2*64*8);
        int mb = ot*16 + quad*4;

        floatx4 acc[2];
        acc[0] = (floatx4){0.f,0.f,0.f,0.f};
        acc[1] = (floatx4){0.f,0.f,0.f,0.f};
        #pragma unroll
        for (int t = 0; t < 9; ++t) {
            int ky = t / 3, kx = t % 3;
            #pragma unroll
            for (int pt = 0; pt < 2; ++pt) {
                bhalf8 bfr = *(const bhalf8*)
                    &rt_[swz((w + ky)*32 + kx + nn + pt*12, quad*8)];
                acc[pt] = __builtin_amdgcn_mfma_f32_16x16x32_bf16(afr[t], bfr, acc[pt], 0, 0, 0);
            }
        }

        int grow = r0 + w;
        #pragma unroll
        for (int pt = 0; pt < 2; ++pt) {
            int pxh = pt*12 + nn;        // 0..27
            float psum = 0.f;
            if (mb < IG) {
                unsigned off = (unsigned)(grow*WW + xb + pxh);
                unsigned pb = planeBase + (unsigned)(mb >> 1);
                uint2 hv = *(const uint2*)&hn[swz((w + 2)*32 + pxh + 2, mb)];
                float h0 = bflo(hv.x) * acc[pt][0];
                float h1 = bfhi(hv.x) * acc[pt][1];
                float h2 = bflo(hv.y) * acc[pt][2];
                float h3 = bfhi(hv.y) * acc[pt][3];
                HupO[(size_t)pb*HWHW + off]     = bf2pack(h0, h1);
                HupO[(size_t)(pb+1)*HWHW + off] = bf2pack(h2, h3);
                psum = h0 + h1 + h2 + h3;
            }
            psum += __shfl_down(psum, 32, 64);
            psum += __shfl_down(psum, 16, 64);
            if (lane < 16) sacc[ot*112 + w*28 + pxh] = psum;
        }
    }
    __syncthreads();
    if (tid < 112) {
        Snxt[(size_t)g*NPIX + n*HWHW + (r0 + tid/28)*WW + xb + (tid % 28)]
            = sacc[tid] + sacc[112 + tid];
    }
}

// ---------------------------------------------------------------------------
// out = x + Hu/(S+EPS); XLNt[px][96] bf16-pairs = LN_cf(out) (eps 1e-5)
__global__ void resln4_kernel(const float* __restrict__ x, const unsigned* __restrict__ Hup,
                              const float* __restrict__ S4,
                              const float* __restrict__ lw, const float* __restrict__ lb,
                              float* __restrict__ out, unsigned* __restrict__ XLNt) {
    int p = blockIdx.x * blockDim.x + threadIdx.x;
    if (p >= NPIX) return;
    int n = p / HWHW, hw = p % HWHW;
    size_t base = (size_t)n*CC_*HWHW + hw;
    float stot = S4[p] + S4[NPIX+p] + S4[2*NPIX+p] + S4[3*NPIX+p];
    float sinv = 1.f / (stot + EPSV);
    float s = 0.f, ss = 0.f;
    for (int c = 0; c < CC_; c += 2) {
        int g = c / IG, pr = (c % IG) >> 1;
        unsigned hu = Hup[(size_t)((n*4+g)*12 + pr)*HWHW + hw];
        float v0 = x[base + (size_t)c*HWHW]     + bflo(hu) * sinv;
        float v1 = x[base + (size_t)(c+1)*HWHW] + bfhi(hu) * sinv;
        out[base + (size_t)c*HWHW]     = v0;
        out[base + (size_t)(c+1)*HWHW] = v1;
        s += v0 + v1; ss += v0*v0 + v1*v1;
    }
    float u  = s * (1.f/CC_);
    float var = ss * (1.f/CC_) - u*u;
    float rs = rsqrtf(var + 1e-5f);
    for (int c = 0; c < CC_; c += 2) {
        float v0 = out[base + (size_t)c*HWHW];
        float v1 = out[base + (size_t)(c+1)*HWHW];
        float a0 = (v0-u)*rs*lw[c]   + lb[c];
        float a1 = (v1-u)*rs*lw[c+1] + lb[c+1];
        XLNt[(size_t)p*48 + (c >> 1)] = bf2pack(a0, a1);
    }
}

// ---------------------------------------------------------------------------
// MFMA MLP (verified round 9): 16 tokens/block, 128 thr.
__global__ __launch_bounds__(128) void mlp5_kernel(
        const ushort_t* __restrict__ XLNt, const ushort_t* __restrict__ w1P,
        const float* __restrict__ b1, const ushort_t* __restrict__ w2P,
        const float* __restrict__ b2, float* __restrict__ out) {
    __shared__ ushort_t lh[16*392];      // 12544 B
    int blk = blockIdx.x;                // 1568
    int tid = threadIdx.x;
    int wv  = tid >> 6, lane = tid & 63;
    int quad = lane >> 4, nn = lane & 15;
    int p0  = blk * 16;
    int n   = p0 / HWHW;
    int hw0 = p0 % HWHW;

    const ushort_t* xrow = XLNt + (size_t)(p0 + nn)*96 + quad*8;
    bhalf8 a1[3];
    #pragma unroll
    for (int ks = 0; ks < 3; ++ks) a1[ks] = *(const bhalf8*)(xrow + ks*32);

    #pragma unroll 1
    for (int i = 0; i < 12; ++i) {
        int nt = wv*12 + i;
        floatx4 acc = (floatx4){0.f,0.f,0.f,0.f};
        #pragma unroll
        for (int ks = 0; ks < 3; ++ks) {
            bhalf8 bfr = *(const bhalf8*)(w1P + ((size_t)(nt*3 + ks)*64 + lane)*8);
            acc = __builtin_amdgcn_mfma_f32_16x16x32_bf16(a1[ks], bfr, acc, 0, 0, 0);
        }
        float b1v = b1[nt*16 + nn];
        #pragma unroll
        for (int r = 0; r < 4; ++r) {
            float h = acc[r] + b1v;
            h = 0.5f * h * (1.f + erff(h * 0.70710678118654752440f));
            lh[(quad*4 + r)*392 + nt*16 + nn] = bf1pack(h);
        }
    }
    __syncthreads();

    bhalf8 bf2[12];
    #pragma unroll
    for (int ks = 0; ks < 12; ++ks)
        bf2[ks] = *(const bhalf8*)&lh[nn*392 + ks*32 + quad*8];

    #pragma unroll 1
    for (int i = 0; i < 3; ++i) {
        int mt = wv*3 + i;
        floatx4 acc = (floatx4){0.f,0.f,0.f,0.f};
        #pragma unroll
        for (int ks = 0; ks < 12; ++ks) {
            bhalf8 af = *(const bhalf8*)(w2P + ((size_t)(mt*12 + ks)*64 + lane)*8);
            acc = __builtin_amdgcn_mfma_f32_16x16x32_bf16(af, bf2[ks], acc, 0, 0, 0);
        }
        #pragma unroll
        for (int r = 0; r < 4; ++r) {
            int c = mt*16 + quad*4 + r;
            size_t addr = ((size_t)n*CC_ + c)*HWHW + hw0 + nn;
            out[addr] += acc[r] + b2[c];
        }
    }
}

// ---------------------------------------------------------------------------
extern "C" void kernel_launch(void* const* d_in, const int* in_sizes, int n_in,
                              void* d_out, int out_size, void* d_ws, size_t ws_size,
                              hipStream_t stream) {
    const float* x    = (const float*)d_in[0];
    const float* ln1w = (const float*)d_in[1];
    const float* ln1b = (const float*)d_in[2];
    const float* wnn  = (const float*)d_in[3];
    const float* ln2w = (const float*)d_in[4];
    const float* ln2b = (const float*)d_in[5];
    const float* w1   = (const float*)d_in[6];
    const float* b1   = (const float*)d_in[7];
    const float* w2   = (const float*)d_in[8];
    const float* b2   = (const float*)d_in[9];
    float* out = (float*)d_out;
    char* ws = (char*)d_ws;

    float*    Wn   = (float*)ws;                      ws += 20736*4;
    ushort_t* WfP  = (ushort_t*)ws;                   ws += 73728*2;
    ushort_t* WtP  = (ushort_t*)ws;                   ws += 73728*2;
    ushort_t* w1P  = (ushort_t*)ws;                   ws += 36864*2;
    ushort_t* w2P  = (ushort_t*)ws;                   ws += 36864*2;
    unsigned* Xp   = (unsigned*)ws;                   ws += (size_t)(NELEM/2)*4;
    unsigned* Hu0  = (unsigned*)ws;                   ws += (size_t)(NELEM/2)*4;
    unsigned* Hu1  = (unsigned*)ws;                   ws += (size_t)(NELEM/2)*4;
    float*    SA   = (float*)ws;                      ws += (size_t)4*NPIX*4;
    float*    SB   = (float*)ws;                      ws += (size_t)4*NPIX*4;
    unsigned* XLNt = (unsigned*)ws;                   ws += (size_t)NPIX*48*4;

    // bf16(1/96) on host (RNE), and the matching per-group channel-sum init
    union { float f; unsigned u; } cv; cv.f = 1.f/96.f;
    unsigned ur = cv.u + 0x7fffu + ((cv.u >> 16) & 1u);
    unsigned short hbits = (unsigned short)(ur >> 16);
    unsigned huInit = ((unsigned)hbits << 16) | hbits;
    union { float f; unsigned u; } hv; hv.u = ((unsigned)hbits) << 16;
    float sInit = 24.f * hv.f;

    wnorm_n_kernel<<<CC_, 256, 0, stream>>>(wnn, Wn);
    wpack_kernel<<<144, 64, 0, stream>>>(Wn, WfP, WtP);
    mlppack_kernel<<<144, 64, 0, stream>>>(w1, w2, w1P, w2P);
    ln1_kernel<<<NPIX/256, 256, 0, stream>>>(x, ln1w, ln1b, Xp);
    // it0 staging is constant-generated in-kernel: no Hu0/SA fills needed.

    for (int it = 0; it < NITER; ++it) {
        const unsigned* HuI  = (it & 1) ? Hu1 : Hu0;
        unsigned*       HuO  = (it & 1) ? Hu0 : Hu1;
        const float*    Scur = (it & 1) ? SB : SA;
        float*          Snxt = (it & 1) ? SA : SB;
        nnmf_mfma_kernel<<<896, 512, 0, stream>>>(HuI, HuO, Scur, Snxt, WtP, WfP, Xp,
                                                  (it == 0) ? 1 : 0, huInit, sInit);
    }
    // 25 iterations: final Hu in Hu1, final S in SB

    resln4_kernel<<<NPIX/256, 256, 0, stream>>>(x, Hu1, SB, ln2w, ln2b, out, XLNt);
    mlp5_kernel<<<NPIX/16, 128, 0, stream>>>((const ushort_t*)XLNt, w1P, b1, w2P, b2, out);
}

// Round 6
// 434.294 us; speedup vs baseline: 1.3349x; 1.3349x over previous
//
#include <hip/hip_runtime.h>
#include <math.h>
#include <string.h>

typedef unsigned short ushort_t;
typedef __attribute__((ext_vector_type(8))) short bhalf8;
typedef __attribute__((ext_vector_type(4))) float floatx4;

// Problem constants
#define NN    8
#define CC_   96
#define HH    56
#define WW    56
#define HWHW  (HH*WW)            // 3136
#define NPIX  (NN*HWHW)          // 25088
#define NELEM (NN*CC_*HWHW)      // 2408448
#define GROUPS 4
#define IG    24                 // channels per group
#define NITER 25
#define EPSV  1e-12f
#define TS    40                 // LDS ch-slot stride (ushorts) = 80 B

// bf16 helpers (RNE)
__device__ __forceinline__ unsigned bf2pack(float a, float b) {
    unsigned ua = __float_as_uint(a), ub = __float_as_uint(b);
    ua += 0x7fffu + ((ua >> 16) & 1u);
    ub += 0x7fffu + ((ub >> 16) & 1u);
    return (ua >> 16) | (ub & 0xffff0000u);
}
__device__ __forceinline__ ushort_t bf1pack(float a) {
    unsigned ua = __float_as_uint(a);
    ua += 0x7fffu + ((ua >> 16) & 1u);
    return (ushort_t)(ua >> 16);
}
__device__ __forceinline__ float bflo(unsigned u) { return __uint_as_float(u << 16); }
__device__ __forceinline__ float bfhi(unsigned u) { return __uint_as_float(u & 0xffff0000u); }

// fast reciprocal: v_rcp_f32 (~1 ulp), error far below bf16 pack rounding
__device__ __forceinline__ float rcpf(float x) {
    float r;
    asm("v_rcp_f32 %0, %1" : "=v"(r) : "v"(x));
    return r;
}

// LDS chunk-XOR swizzle: slot stride TS=40 ushorts (80B); data = 4 chunks of
// 16B (u = 0..31). chunk' = chunk ^ ((slot>>3)&3) makes the lanes nn / nn+8
// (slot delta 8) map to disjoint 4-bank sets on ds_read_b128. Bijective per
// slot; all accesses stay within one 16B chunk, so writes/reads stay paired.
__device__ __forceinline__ int swz(int slot, int u) {
    return slot*TS + ((((u >> 3) ^ (slot >> 3)) & 3) << 3) + (u & 7);
}

// ---------------------------------------------------------------------------
// Normalize weights -> Wn[96][216] fp32
__global__ void wnorm_n_kernel(const float* __restrict__ w_in, float* __restrict__ Wn) {
    int o = blockIdx.x;
    int t = threadIdx.x;
    float myv = (t < 216) ? fabsf(w_in[o*216 + t]) : 0.f;
    float v = myv;
    #pragma unroll
    for (int off = 32; off; off >>= 1) v += __shfl_down(v, off, 64);
    __shared__ float red[4];
    if ((t & 63) == 0) red[t >> 6] = v;
    __syncthreads();
    float s = red[0] + red[1] + red[2] + red[3];
    if (t < 216) Wn[o*216 + t] = myv / (s + EPSV);
}

// ---------------------------------------------------------------------------
// Pack conv A-fragments (bf16) for MFMA 16x16x32 (verified round 7/9).
__global__ void wpack_kernel(const float* __restrict__ Wn,
                             ushort_t* __restrict__ WfP, ushort_t* __restrict__ WtP) {
    int bi = blockIdx.x;             // 144 = 2 sel * 72
    int sel = bi / 72;
    int rem = bi % 72;
    int ot = rem & 1;
    int gt = rem >> 1;               // g*9 + tap
    int g = gt / 9, tap = gt % 9;
    int lane = threadIdx.x;
    int quad = lane >> 4, nn = lane & 15;
    int m = ot*16 + nn;
    ushort_t v[8];
    #pragma unroll
    for (int j = 0; j < 8; ++j) {
        int kc = quad*8 + j;
        float val = 0.f;
        if (m < IG && kc < IG) {
            if (sel == 0) val = Wn[(g*IG + m)*216 + kc*9 + tap];
            else          val = Wn[(g*IG + kc)*216 + m*9 + (8 - tap)];
        }
        v[j] = bf1pack(val);
    }
    ushort_t* dst = (sel ? WtP : WfP) + ((size_t)(gt*2 + ot)*64 + lane)*8;
    *(uint4*)dst = *(uint4*)v;
}

// ---------------------------------------------------------------------------
// Pack MLP weight fragments (verified round 9).
__global__ void mlppack_kernel(const float* __restrict__ w1, const float* __restrict__ w2,
                               ushort_t* __restrict__ w1P, ushort_t* __restrict__ w2P) {
    int f = blockIdx.x;              // 144: 72 for w1 (24nt*3ks), 72 for w2 (6mt*12ks)
    int lane = threadIdx.x;
    int quad = lane >> 4, nn = lane & 15;
    ushort_t v[8];
    if (f < 72) {
        int nt = f / 3, ks = f % 3;
        #pragma unroll
        for (int j = 0; j < 8; ++j)
            v[j] = bf1pack(w1[(size_t)(ks*32 + quad*8 + j)*384 + nt*16 + nn]);
        *(uint4*)(w1P + ((size_t)f*64 + lane)*8) = *(uint4*)v;
    } else {
        int f2 = f - 72;
        int mt = f2 / 12, ks = f2 % 12;
        #pragma unroll
        for (int j = 0; j < 8; ++j)
            v[j] = bf1pack(w2[(size_t)(ks*32 + quad*8 + j)*96 + mt*16 + nn]);
        *(uint4*)(w2P + ((size_t)f2*64 + lane)*8) = *(uint4*)v;
    }
}

// ---------------------------------------------------------------------------
// LN1 -> relu -> channel-normalize => Xp (bf16 channel-pairs).
__global__ void ln1_kernel(const float* __restrict__ x, const float* __restrict__ lw,
                           const float* __restrict__ lb, unsigned* __restrict__ Xp) {
    int p = blockIdx.x * blockDim.x + threadIdx.x;
    if (p >= NPIX) return;
    int n = p / HWHW, hw = p % HWHW;
    const float* xp = x + (size_t)n*CC_*HWHW + hw;
    float s = 0.f, ss = 0.f;
    for (int c = 0; c < CC_; ++c) { float v = xp[(size_t)c*HWHW]; s += v; ss += v*v; }
    float u  = s * (1.f/CC_);
    float var = ss * (1.f/CC_) - u*u;
    float rs = rsqrtf(var + 1e-6f);
    float sr = 0.f;
    for (int c = 0; c < CC_; ++c) {
        float v = xp[(size_t)c*HWHW];
        float a = fmaxf((v-u)*rs*lw[c] + lb[c], 0.f);
        sr += a;
    }
    float inv = 1.f / (sr + EPSV);
    for (int c = 0; c < CC_; c += 2) {
        float v0 = xp[(size_t)c*HWHW];
        float v1 = xp[(size_t)(c+1)*HWHW];
        float a0 = fmaxf((v0-u)*rs*lw[c] + lb[c], 0.f) * inv;
        float a1 = fmaxf((v1-u)*rs*lw[c+1] + lb[c+1], 0.f) * inv;
        int g = c / IG, pr = (c % IG) >> 1;
        Xp[(size_t)((n*4+g)*12 + pr)*HWHW + hw] = bf2pack(a0, a1);
    }
}

// ---------------------------------------------------------------------------
// Fused NNMF iteration (MFMA), 7-row band tile, 25 launches (1 per iteration).
// Round 14: UNIFORM OCCUPANCY. 8 bands x 2 halves x 32 (n,g) = 512 blocks =
// exactly 2 blocks/CU on all 256 CUs (R3 had 448 -> 64 CUs half-idle).
// LDS 54.2KB/block <= 80KB; __launch_bounds__(512,4) => VGPR <= 128.
// Same proven phase structure as R3 (ot-split B, swizzle, rcp, it0-const).
// XCD-locality: all 16 tiles of an (n,g) group land on one XCD.
__global__ __launch_bounds__(512, 4) void nnmf_mfma_kernel(
        const unsigned* __restrict__ HupI, unsigned* __restrict__ HupO,
        const float* __restrict__ Scur, float* __restrict__ Snxt,
        const ushort_t* __restrict__ WtP, const ushort_t* __restrict__ WfP,
        const unsigned* __restrict__ Xp,
        int it0, unsigned huInit, float sInit) {
    __shared__ ushort_t hn[352*TS];      // HuN tile [row11*32+pos][40]  28160 B
    __shared__ ushort_t rt_[288*TS];     // R   tile [row9*32+pos][40]   23040 B
    __shared__ float sinv[352];
    __shared__ float sacc[392];
    int b    = blockIdx.x;               // 512
    // XCD-aware decode: xcd = b&7, 4 ng-groups x 16 tiles per XCD
    int k_   = b >> 3;                   // 0..63
    int ng   = (b & 7)*4 + (k_ >> 4);    // 0..31
    int tile = k_ & 15;                  // 0..15
    int rtb  = tile >> 1;                // 0..7 (7-row bands)
    int half = tile & 1;
    int n    = ng >> 2;
    int g    = ng & 3;
    int tid  = threadIdx.x;
    int r0   = rtb*7;
    int xb   = half*28;
    unsigned planeBase = (unsigned)(n*4 + g)*12;

    int waveId = tid >> 6, lane = tid & 63;
    int quad = lane >> 4, nn = lane & 15;
    int otB = waveId & 1;
    int mbB = otB*16 + quad*4;           // phase-B output channel base

    // convT weight frags early: latency overlaps staging (ot-split: 9 frags)
    bhalf8 afrB[9];
    {
        const ushort_t* ap = WtP + ((size_t)(g*9*2 + otB)*64 + lane)*8;
        #pragma unroll
        for (int t = 0; t < 9; ++t) afrB[t] = *(const bhalf8*)(ap + (size_t)t*2*64*8);
    }

    // ---- prefetch Hu staging loads (independent of sinv) to hide L2 latency
    // 11x32 grid = 352 slots, 6 data pr2 => 2112 elements (kk 0..4, guarded)
    uint2 raw[5];
    #pragma unroll
    for (int kk = 0; kk < 5; ++kk) {
        int idx  = tid + kk*512;         // 0..2559
        int pr2  = idx / 352;            // 0..7 (6 used)
        int slot = idx - pr2*352;        // 0..351
        int r = slot >> 5, q = slot & 31;
        int gr = r0 - 2 + r, gc = xb - 2 + q;
        uint2 rv = {0u, 0u};
        if (!it0 && pr2 < 6 && gr >= 0 && gr < HH && gc >= 0 && gc < WW) {
            unsigned off = (unsigned)(gr*WW + gc);
            rv.x = HupI[(size_t)(planeBase + 2*pr2)*HWHW + off];
            rv.y = HupI[(size_t)(planeBase + 2*pr2 + 1)*HWHW + off];
        }
        raw[kk] = rv;
    }

    // ---- sinv for the 11x32 staging grid (gr = r0-2+r, gc = xb-2+q)
    if (tid < 352) {
        int r = tid >> 5, q = tid & 31;
        int gr = r0 - 2 + r, gc = xb - 2 + q;
        float st = 1.f;
        if (gr >= 0 && gr < HH && gc >= 0 && gc < WW) {
            if (it0) {
                st = 4.f*sInit;          // == sum of 4 filled planes, exact
            } else {
                unsigned p = (unsigned)(n*HWHW + gr*WW + gc);
                st = Scur[p] + Scur[NPIX+p] + Scur[2*NPIX+p] + Scur[3*NPIX+p];
            }
        }
        sinv[tid] = rcpf(st + EPSV);
    }
    __syncthreads();

    // ---- stage HuN (bf16 in -> *si -> bf16); pr2 6,7 zero the K-pad chunks
    #pragma unroll
    for (int kk = 0; kk < 6; ++kk) {
        int idx  = tid + kk*512;         // need idx < 2816 (8 pr2 x 352)
        if (idx < 2816) {
            int pr2  = idx / 352;
            int slot = idx - pr2*352;
            int r = slot >> 5, q = slot & 31;
            int gr = r0 - 2 + r, gc = xb - 2 + q;
            uint2 pk = {0u, 0u};
            if (pr2 < 6 && gr >= 0 && gr < HH && gc >= 0 && gc < WW) {
                float si = sinv[slot];
                if (it0) {
                    float hval = bflo(huInit) * si;
                    pk.x = bf2pack(hval, hval);
                    pk.y = pk.x;
                } else {
                    pk.x = bf2pack(bflo(raw[kk].x)*si, bfhi(raw[kk].x)*si);
                    pk.y = bf2pack(bflo(raw[kk].y)*si, bfhi(raw[kk].y)*si);
                }
            }
            *(uint2*)&hn[swz(slot, 4*pr2)] = pk;
        }
    }
    if (tid < 288) *(uint4*)&rt_[swz(tid, 24)] = (uint4){0u,0u,0u,0u};
    __syncthreads();

    // ---- Phase B: convT -> R band (9 rows x 30 px) in LDS; 36 tasks
    {
        #pragma unroll
        for (int i = 0; i < 5; ++i) {
            int tk = waveId + 8*i;       // 0..39, valid < 36; tk&1 == otB
            if (tk < 36) {
                int pt  = (tk >> 1) & 1;
                int row = tk >> 2;       // 0..8 (gr = r0-1+row)
                int x0R = pt*14;
                // hoisted ratio operands
                unsigned xa = 0u, xc = 0u;
                int gr = r0 - 1 + row, gc = xb - 1 + x0R + nn;
                if (mbB < IG && gr >= 0 && gr < HH && gc >= 0 && gc < WW) {
                    unsigned off = (unsigned)(gr*WW + gc);
                    unsigned pb = planeBase + (unsigned)(mbB >> 1);
                    xa = Xp[(size_t)pb*HWHW + off];
                    xc = Xp[(size_t)(pb+1)*HWHW + off];
                }
                floatx4 acc = (floatx4){0.f,0.f,0.f,0.f};
                #pragma unroll
                for (int t = 0; t < 9; ++t) {
                    int ky = t / 3, kx = t % 3;
                    bhalf8 bfr = *(const bhalf8*)
                        &hn[swz((row + ky)*32 + kx + nn + x0R, quad*8)];
                    acc = __builtin_amdgcn_mfma_f32_16x16x32_bf16(afrB[t], bfr, acc, 0, 0, 0);
                }
                if (mbB < IG) {
                    int slot = row*32 + x0R + nn;
                    *(unsigned*)&rt_[swz(slot, mbB)] =
                        bf2pack(bflo(xa)*rcpf(acc[0]+EPSV), bfhi(xa)*rcpf(acc[1]+EPSV));
                    *(unsigned*)&rt_[swz(slot, mbB + 2)] =
                        bf2pack(bflo(xc)*rcpf(acc[2]+EPSV), bfhi(xc)*rcpf(acc[3]+EPSV));
                }
            }
        }
    }
    __syncthreads();

    // ---- Phase C: forward conv + multiplicative update; 28 tasks (7r x 2xt x 2ot)
    {
        const ushort_t* ap = WfP + ((size_t)(g*9*2 + otB)*64 + lane)*8;
        bhalf8 afr[9];
        #pragma unroll
        for (int t = 0; t < 9; ++t) afr[t] = *(const bhalf8*)(ap + (size_t)t*2*64*8);
        int mb = mbB;

        #pragma unroll
        for (int i = 0; i < 4; ++i) {
            int tc = waveId + 8*i;       // 0..31, valid < 28; tc&1 == otB
            if (tc < 28) {
                int xt = (tc >> 1) & 1;
                int w  = tc >> 2;        // out row in band, 0..6
                int px0 = xt*12;
                floatx4 acc = (floatx4){0.f,0.f,0.f,0.f};
                #pragma unroll
                for (int t = 0; t < 9; ++t) {
                    int ky = t / 3, kx = t % 3;
                    bhalf8 bfr = *(const bhalf8*)
                        &rt_[swz((w + ky)*32 + kx + nn + px0, quad*8)];
                    acc = __builtin_amdgcn_mfma_f32_16x16x32_bf16(afr[t], bfr, acc, 0, 0, 0);
                }

                int grow = r0 + w;
                int pxh = px0 + nn;      // 0..27 (overlap 12..15 identical)
                float psum = 0.f;
                if (mb < IG) {
                    unsigned off = (unsigned)(grow*WW + xb + pxh);
                    unsigned pb = planeBase + (unsigned)(mb >> 1);
                    uint2 hv = *(const uint2*)&hn[swz((w + 2)*32 + pxh + 2, mb)];
                    float h0 = bflo(hv.x) * acc[0];
                    float h1 = bfhi(hv.x) * acc[1];
                    float h2 = bflo(hv.y) * acc[2];
                    float h3 = bfhi(hv.y) * acc[3];
                    HupO[(size_t)pb*HWHW + off]     = bf2pack(h0, h1);
                    HupO[(size_t)(pb+1)*HWHW + off] = bf2pack(h2, h3);
                    psum = h0 + h1 + h2 + h3;
                }
                psum += __shfl_down(psum, 32, 64);
                psum += __shfl_down(psum, 16, 64);
                if (lane < 16) sacc[otB*196 + w*28 + pxh] = psum;
            }
        }
    }
    __syncthreads();
    if (tid < 196) {
        Snxt[(size_t)g*NPIX + n*HWHW + (r0 + tid/28)*WW + xb + (tid % 28)]
            = sacc[tid] + sacc[196 + tid];
    }
}

// ---------------------------------------------------------------------------
// out = x + Hu/(S+EPS); XLNt[px][96] bf16-pairs = LN_cf(out) (eps 1e-5)
__global__ void resln4_kernel(const float* __restrict__ x, const unsigned* __restrict__ Hup,
                              const float* __restrict__ S4,
                              const float* __restrict__ lw, const float* __restrict__ lb,
                              float* __restrict__ out, unsigned* __restrict__ XLNt) {
    int p = blockIdx.x * blockDim.x + threadIdx.x;
    if (p >= NPIX) return;
    int n = p / HWHW, hw = p % HWHW;
    size_t base = (size_t)n*CC_*HWHW + hw;
    float stot = S4[p] + S4[NPIX+p] + S4[2*NPIX+p] + S4[3*NPIX+p];
    float sinv = 1.f / (stot + EPSV);
    float s = 0.f, ss = 0.f;
    for (int c = 0; c < CC_; c += 2) {
        int g = c / IG, pr = (c % IG) >> 1;
        unsigned hu = Hup[(size_t)((n*4+g)*12 + pr)*HWHW + hw];
        float v0 = x[base + (size_t)c*HWHW]     + bflo(hu) * sinv;
        float v1 = x[base + (size_t)(c+1)*HWHW] + bfhi(hu) * sinv;
        out[base + (size_t)c*HWHW]     = v0;
        out[base + (size_t)(c+1)*HWHW] = v1;
        s += v0 + v1; ss += v0*v0 + v1*v1;
    }
    float u  = s * (1.f/CC_);
    float var = ss * (1.f/CC_) - u*u;
    float rs = rsqrtf(var + 1e-5f);
    for (int c = 0; c < CC_; c += 2) {
        float v0 = out[base + (size_t)c*HWHW];
        float v1 = out[base + (size_t)(c+1)*HWHW];
        float a0 = (v0-u)*rs*lw[c]   + lb[c];
        float a1 = (v1-u)*rs*lw[c+1] + lb[c+1];
        XLNt[(size_t)p*48 + (c >> 1)] = bf2pack(a0, a1);
    }
}

// ---------------------------------------------------------------------------
// MFMA MLP (verified round 9): 16 tokens/block, 128 thr.
__global__ __launch_bounds__(128) void mlp5_kernel(
        const ushort_t* __restrict__ XLNt, const ushort_t* __restrict__ w1P,
        const float* __restrict__ b1, const ushort_t* __restrict__ w2P,
        const float* __restrict__ b2, float* __restrict__ out) {
    __shared__ ushort_t lh[16*392];      // 12544 B
    int blk = blockIdx.x;                // 1568
    int tid = threadIdx.x;
    int wv  = tid >> 6, lane = tid & 63;
    int quad = lane >> 4, nn = lane & 15;
    int p0  = blk * 16;
    int n   = p0 / HWHW;
    int hw0 = p0 % HWHW;

    const ushort_t* xrow = XLNt + (size_t)(p0 + nn)*96 + quad*8;
    bhalf8 a1[3];
    #pragma unroll
    for (int ks = 0; ks < 3; ++ks) a1[ks] = *(const bhalf8*)(xrow + ks*32);

    #pragma unroll 1
    for (int i = 0; i < 12; ++i) {
        int nt = wv*12 + i;
        floatx4 acc = (floatx4){0.f,0.f,0.f,0.f};
        #pragma unroll
        for (int ks = 0; ks < 3; ++ks) {
            bhalf8 bfr = *(const bhalf8*)(w1P + ((size_t)(nt*3 + ks)*64 + lane)*8);
            acc = __builtin_amdgcn_mfma_f32_16x16x32_bf16(a1[ks], bfr, acc, 0, 0, 0);
        }
        float b1v = b1[nt*16 + nn];
        #pragma unroll
        for (int r = 0; r < 4; ++r) {
            float h = acc[r] + b1v;
            h = 0.5f * h * (1.f + erff(h * 0.70710678118654752440f));
            lh[(quad*4 + r)*392 + nt*16 + nn] = bf1pack(h);
        }
    }
    __syncthreads();

    bhalf8 bf2[12];
    #pragma unroll
    for (int ks = 0; ks < 12; ++ks)
        bf2[ks] = *(const bhalf8*)&lh[nn*392 + ks*32 + quad*8];

    #pragma unroll 1
    for (int i = 0; i < 3; ++i) {
        int mt = wv*3 + i;
        floatx4 acc = (floatx4){0.f,0.f,0.f,0.f};
        #pragma unroll
        for (int ks = 0; ks < 12; ++ks) {
            bhalf8 af = *(const bhalf8*)(w2P + ((size_t)(mt*12 + ks)*64 + lane)*8);
            acc = __builtin_amdgcn_mfma_f32_16x16x32_bf16(af, bf2[ks], acc, 0, 0, 0);
        }
        #pragma unroll
        for (int r = 0; r < 4; ++r) {
            int c = mt*16 + quad*4 + r;
            size_t addr = ((size_t)n*CC_ + c)*HWHW + hw0 + nn;
            out[addr] += acc[r] + b2[c];
        }
    }
}

// ---------------------------------------------------------------------------
extern "C" void kernel_launch(void* const* d_in, const int* in_sizes, int n_in,
                              void* d_out, int out_size, void* d_ws, size_t ws_size,
                              hipStream_t stream) {
    const float* x    = (const float*)d_in[0];
    const float* ln1w = (const float*)d_in[1];
    const float* ln1b = (const float*)d_in[2];
    const float* wnn  = (const float*)d_in[3];
    const float* ln2w = (const float*)d_in[4];
    const float* ln2b = (const float*)d_in[5];
    const float* w1   = (const float*)d_in[6];
    const float* b1   = (const float*)d_in[7];
    const float* w2   = (const float*)d_in[8];
    const float* b2   = (const float*)d_in[9];
    float* out = (float*)d_out;
    char* ws = (char*)d_ws;

    float*    Wn   = (float*)ws;                      ws += 20736*4;
    ushort_t* WfP  = (ushort_t*)ws;                   ws += 73728*2;
    ushort_t* WtP  = (ushort_t*)ws;                   ws += 73728*2;
    ushort_t* w1P  = (ushort_t*)ws;                   ws += 36864*2;
    ushort_t* w2P  = (ushort_t*)ws;                   ws += 36864*2;
    unsigned* Xp   = (unsigned*)ws;                   ws += (size_t)(NELEM/2)*4;
    unsigned* Hu0  = (unsigned*)ws;                   ws += (size_t)(NELEM/2)*4;
    unsigned* Hu1  = (unsigned*)ws;                   ws += (size_t)(NELEM/2)*4;
    float*    SA   = (float*)ws;                      ws += (size_t)4*NPIX*4;
    float*    SB   = (float*)ws;                      ws += (size_t)4*NPIX*4;
    unsigned* XLNt = (unsigned*)ws;                   ws += (size_t)NPIX*48*4;

    // bf16(1/96) on host (RNE), and the matching per-group channel-sum init
    union { float f; unsigned u; } cv; cv.f = 1.f/96.f;
    unsigned ur = cv.u + 0x7fffu + ((cv.u >> 16) & 1u);
    unsigned short hbits = (unsigned short)(ur >> 16);
    unsigned huInit = ((unsigned)hbits << 16) | hbits;
    union { float f; unsigned u; } hv; hv.u = ((unsigned)hbits) << 16;
    float sInit = 24.f * hv.f;

    wnorm_n_kernel<<<CC_, 256, 0, stream>>>(wnn, Wn);
    wpack_kernel<<<144, 64, 0, stream>>>(Wn, WfP, WtP);
    mlppack_kernel<<<144, 64, 0, stream>>>(w1, w2, w1P, w2P);
    ln1_kernel<<<NPIX/256, 256, 0, stream>>>(x, ln1w, ln1b, Xp);
    // it0 staging is constant-generated in-kernel: no Hu0/SA fills needed.

    for (int it = 0; it < NITER; ++it) {
        const unsigned* HuI  = (it & 1) ? Hu1 : Hu0;
        unsigned*       HuO  = (it & 1) ? Hu0 : Hu1;
        const float*    Scur = (it & 1) ? SB : SA;
        float*          Snxt = (it & 1) ? SA : SB;
        nnmf_mfma_kernel<<<512, 512, 0, stream>>>(HuI, HuO, Scur, Snxt, WtP, WfP, Xp,
                                                  (it == 0) ? 1 : 0, huInit, sInit);
    }
    // 25 iterations: final Hu in Hu1, final S in SB

    resln4_kernel<<<NPIX/256, 256, 0, stream>>>(x, Hu1, SB, ln2w, ln2b, out, XLNt);
    mlp5_kernel<<<NPIX/16, 128, 0, stream>>>((const ushort_t*)XLNt, w1P, b1, w2P, b2, out);
}

// Round 7
// 402.709 us; speedup vs baseline: 1.4396x; 1.0784x over previous
//
#include <hip/hip_runtime.h>
#include <math.h>
#include <string.h>

typedef unsigned short ushort_t;
typedef __attribute__((ext_vector_type(8))) short bhalf8;
typedef __attribute__((ext_vector_type(4))) float floatx4;

// Problem constants
#define NN    8
#define CC_   96
#define HH    56
#define WW    56
#define HWHW  (HH*WW)            // 3136
#define NPIX  (NN*HWHW)          // 25088
#define NELEM (NN*CC_*HWHW)      // 2408448
#define GROUPS 4
#define IG    24                 // channels per group
#define NITER 25
#define EPSV  1e-12f
#define TS    40                 // LDS ch-slot stride (ushorts) = 80 B

// bf16 helpers (RNE)
__device__ __forceinline__ unsigned bf2pack(float a, float b) {
    unsigned ua = __float_as_uint(a), ub = __float_as_uint(b);
    ua += 0x7fffu + ((ua >> 16) & 1u);
    ub += 0x7fffu + ((ub >> 16) & 1u);
    return (ua >> 16) | (ub & 0xffff0000u);
}
__device__ __forceinline__ ushort_t bf1pack(float a) {
    unsigned ua = __float_as_uint(a);
    ua += 0x7fffu + ((ua >> 16) & 1u);
    return (ushort_t)(ua >> 16);
}
__device__ __forceinline__ float bflo(unsigned u) { return __uint_as_float(u << 16); }
__device__ __forceinline__ float bfhi(unsigned u) { return __uint_as_float(u & 0xffff0000u); }

// fast reciprocal: v_rcp_f32 (~1 ulp), error far below bf16 pack rounding
__device__ __forceinline__ float rcpf(float x) {
    float r;
    asm("v_rcp_f32 %0, %1" : "=v"(r) : "v"(x));
    return r;
}

// LDS chunk-XOR swizzle: slot stride TS=40 ushorts (80B); data = 4 chunks of
// 16B (u = 0..31). chunk' = chunk ^ ((slot>>3)&3) makes the lanes nn / nn+8
// (slot delta 8) map to disjoint 4-bank sets on ds_read_b128. Bijective per
// slot; all accesses stay within one 16B chunk, so writes/reads stay paired.
__device__ __forceinline__ int swz(int slot, int u) {
    return slot*TS + ((((u >> 3) ^ (slot >> 3)) & 3) << 3) + (u & 7);
}

// ---------------------------------------------------------------------------
// Fused prep: blocks 0-3   = wnorm+wpack (per group g)
//             blocks 4-39  = mlppack (4 frag-sets per block)
//             blocks 40-137= ln1 (256 px per block)
__global__ __launch_bounds__(256) void prep_kernel(
        const float* __restrict__ w_in,
        ushort_t* __restrict__ WfP, ushort_t* __restrict__ WtP,
        const float* __restrict__ w1, const float* __restrict__ w2,
        ushort_t* __restrict__ w1P, ushort_t* __restrict__ w2P,
        const float* __restrict__ x, const float* __restrict__ lw1,
        const float* __restrict__ lb1, unsigned* __restrict__ Xp) {
    __shared__ float wn[24*216];         // 20736 B
    __shared__ float rsum[24];
    int b = blockIdx.x;
    int tid = threadIdx.x;

    if (b < 4) {
        int g = b;
        // ---- weight L1-normalize for this group's 24 output channels
        if (tid < 24) {
            const float* wr = w_in + (size_t)(g*24 + tid)*216;
            float s = 0.f;
            for (int j = 0; j < 216; ++j) s += fabsf(wr[j]);
            rsum[tid] = s;
        }
        __syncthreads();
        for (int i = tid; i < 24*216; i += 256) {
            int row = i / 216;
            wn[i] = fabsf(w_in[(size_t)g*24*216 + i]) * rcpf(rsum[row] + EPSV);
        }
        __syncthreads();
        // ---- pack conv A-fragments (both sel, both ot, 9 taps)
        int lg = tid >> 6;               // 0..3
        int lane = tid & 63;
        int quad = lane >> 4, nn15 = lane & 15;
        #pragma unroll 1
        for (int i = 0; i < 9; ++i) {
            int fr  = lg + 4*i;          // 0..35
            int sel = fr / 18;
            int rem = fr % 18;
            int ot  = rem & 1;
            int tap = rem >> 1;
            int m = ot*16 + nn15;
            ushort_t v[8];
            #pragma unroll
            for (int j = 0; j < 8; ++j) {
                int kc = quad*8 + j;
                float val = 0.f;
                if (m < IG && kc < IG) {
                    if (sel == 0) val = wn[m*216 + kc*9 + tap];
                    else          val = wn[kc*216 + m*9 + (8 - tap)];
                }
                v[j] = bf1pack(val);
            }
            ushort_t* dst = (sel ? WtP : WfP) + ((size_t)((g*9 + tap)*2 + ot)*64 + lane)*8;
            *(uint4*)dst = *(uint4*)v;
        }
    } else if (b < 40) {
        // ---- MLP weight fragments
        int f = (b - 4)*4 + (tid >> 6);  // 0..143
        int lane = tid & 63;
        int quad = lane >> 4, nn15 = lane & 15;
        ushort_t v[8];
        if (f < 72) {
            int nt = f / 3, ks = f % 3;
            #pragma unroll
            for (int j = 0; j < 8; ++j)
                v[j] = bf1pack(w1[(size_t)(ks*32 + quad*8 + j)*384 + nt*16 + nn15]);
            *(uint4*)(w1P + ((size_t)f*64 + lane)*8) = *(uint4*)v;
        } else {
            int f2 = f - 72;
            int mt = f2 / 12, ks = f2 % 12;
            #pragma unroll
            for (int j = 0; j < 8; ++j)
                v[j] = bf1pack(w2[(size_t)(ks*32 + quad*8 + j)*96 + mt*16 + nn15]);
            *(uint4*)(w2P + ((size_t)f2*64 + lane)*8) = *(uint4*)v;
        }
    } else {
        // ---- LN1 -> relu -> channel-normalize => Xp
        int p = (b - 40)*256 + tid;      // < NPIX exactly
        int n = p / HWHW, hw = p % HWHW;
        const float* xp = x + (size_t)n*CC_*HWHW + hw;
        float s = 0.f, ss = 0.f;
        for (int c = 0; c < CC_; ++c) { float v = xp[(size_t)c*HWHW]; s += v; ss += v*v; }
        float u  = s * (1.f/CC_);
        float var = ss * (1.f/CC_) - u*u;
        float rs = rsqrtf(var + 1e-6f);
        float sr = 0.f;
        for (int c = 0; c < CC_; ++c) {
            float v = xp[(size_t)c*HWHW];
            float a = fmaxf((v-u)*rs*lw1[c] + lb1[c], 0.f);
            sr += a;
        }
        float inv = 1.f / (sr + EPSV);
        for (int c = 0; c < CC_; c += 2) {
            float v0 = xp[(size_t)c*HWHW];
            float v1 = xp[(size_t)(c+1)*HWHW];
            float a0 = fmaxf((v0-u)*rs*lw1[c] + lb1[c], 0.f) * inv;
            float a1 = fmaxf((v1-u)*rs*lw1[c+1] + lb1[c+1], 0.f) * inv;
            int g = c / IG, pr = (c % IG) >> 1;
            Xp[(size_t)((n*4+g)*12 + pr)*HWHW + hw] = bf2pack(a0, a1);
        }
    }
}

// ---------------------------------------------------------------------------
// Fused NNMF iteration (MFMA), 7-row band tile, 25 launches (1 per iteration).
// R6 structure (512 blocks = uniform 2/CU) + R7: sinv folded into staging
// (per-element S loads, L1-resident) -> one barrier fewer (3 vs 4).
__global__ __launch_bounds__(512, 4) void nnmf_mfma_kernel(
        const unsigned* __restrict__ HupI, unsigned* __restrict__ HupO,
        const float* __restrict__ Scur, float* __restrict__ Snxt,
        const ushort_t* __restrict__ WtP, const ushort_t* __restrict__ WfP,
        const unsigned* __restrict__ Xp,
        int it0, unsigned huInit, float sInit) {
    __shared__ ushort_t hn[352*TS];      // HuN tile [row11*32+pos][40]  28160 B
    __shared__ ushort_t rt_[288*TS];     // R   tile [row9*32+pos][40]   23040 B
    __shared__ float sacc[392];
    int b    = blockIdx.x;               // 512
    // XCD-aware decode: xcd = b&7, 4 ng-groups x 16 tiles per XCD
    int k_   = b >> 3;                   // 0..63
    int ng   = (b & 7)*4 + (k_ >> 4);    // 0..31
    int tile = k_ & 15;                  // 0..15
    int rtb  = tile >> 1;                // 0..7 (7-row bands)
    int half = tile & 1;
    int n    = ng >> 2;
    int g    = ng & 3;
    int tid  = threadIdx.x;
    int r0   = rtb*7;
    int xb   = half*28;
    unsigned planeBase = (unsigned)(n*4 + g)*12;

    int waveId = tid >> 6, lane = tid & 63;
    int quad = lane >> 4, nn = lane & 15;
    int otB = waveId & 1;
    int mbB = otB*16 + quad*4;           // phase-B output channel base

    // convT weight frags early: latency overlaps staging (ot-split: 9 frags)
    bhalf8 afrB[9];
    {
        const ushort_t* ap = WtP + ((size_t)(g*9*2 + otB)*64 + lane)*8;
        #pragma unroll
        for (int t = 0; t < 9; ++t) afrB[t] = *(const bhalf8*)(ap + (size_t)t*2*64*8);
    }

    // ---- prefetch Hu + S for staging (11x32 grid = 352 slots, 6 data pr2)
    uint2 raw[6];
    float sA[6], sB[6], sC[6], sD[6];
    #pragma unroll
    for (int kk = 0; kk < 6; ++kk) {
        int idx = tid + kk*512;          // < 2816 guarded
        uint2 rv = {0u, 0u};
        float a0 = 0.f, a1 = 0.f, a2 = 0.f, a3 = 0.f;
        if (idx < 2816) {
            int pr2  = idx / 352;        // 0..7 (6 used)
            int slot = idx - pr2*352;    // 0..351
            int r = slot >> 5, q = slot & 31;
            int gr = r0 - 2 + r, gc = xb - 2 + q;
            if (!it0 && pr2 < 6 && gr >= 0 && gr < HH && gc >= 0 && gc < WW) {
                unsigned off = (unsigned)(gr*WW + gc);
                unsigned pix = (unsigned)(n*HWHW) + off;
                rv.x = HupI[(size_t)(planeBase + 2*pr2)*HWHW + off];
                rv.y = HupI[(size_t)(planeBase + 2*pr2 + 1)*HWHW + off];
                a0 = Scur[pix];
                a1 = Scur[NPIX + pix];
                a2 = Scur[2*NPIX + pix];
                a3 = Scur[3*NPIX + pix];
            }
        }
        raw[kk] = rv;
        sA[kk] = a0; sB[kk] = a1; sC[kk] = a2; sD[kk] = a3;
    }

    // ---- stage HuN = Hu/S (bf16); pr2 6,7 zero the K-pad chunks
    #pragma unroll
    for (int kk = 0; kk < 6; ++kk) {
        int idx = tid + kk*512;
        if (idx < 2816) {
            int pr2  = idx / 352;
            int slot = idx - pr2*352;
            int r = slot >> 5, q = slot & 31;
            int gr = r0 - 2 + r, gc = xb - 2 + q;
            uint2 pk = {0u, 0u};
            if (pr2 < 6 && gr >= 0 && gr < HH && gc >= 0 && gc < WW) {
                if (it0) {
                    float si = rcpf(4.f*sInit + EPSV);
                    float hval = bflo(huInit) * si;
                    pk.x = bf2pack(hval, hval);
                    pk.y = pk.x;
                } else {
                    float st = sA[kk] + sB[kk] + sC[kk] + sD[kk];
                    float si = rcpf(st + EPSV);
                    pk.x = bf2pack(bflo(raw[kk].x)*si, bfhi(raw[kk].x)*si);
                    pk.y = bf2pack(bflo(raw[kk].y)*si, bfhi(raw[kk].y)*si);
                }
            }
            *(uint2*)&hn[swz(slot, 4*pr2)] = pk;
        }
    }
    if (tid < 288) *(uint4*)&rt_[swz(tid, 24)] = (uint4){0u,0u,0u,0u};
    __syncthreads();

    // ---- Phase B: convT -> R band (9 rows x 30 px) in LDS; 36 tasks
    {
        #pragma unroll
        for (int i = 0; i < 5; ++i) {
            int tk = waveId + 8*i;       // 0..39, valid < 36; tk&1 == otB
            if (tk < 36) {
                int pt  = (tk >> 1) & 1;
                int row = tk >> 2;       // 0..8 (gr = r0-1+row)
                int x0R = pt*14;
                // hoisted ratio operands
                unsigned xa = 0u, xc = 0u;
                int gr = r0 - 1 + row, gc = xb - 1 + x0R + nn;
                if (mbB < IG && gr >= 0 && gr < HH && gc >= 0 && gc < WW) {
                    unsigned off = (unsigned)(gr*WW + gc);
                    unsigned pb = planeBase + (unsigned)(mbB >> 1);
                    xa = Xp[(size_t)pb*HWHW + off];
                    xc = Xp[(size_t)(pb+1)*HWHW + off];
                }
                floatx4 acc = (floatx4){0.f,0.f,0.f,0.f};
                #pragma unroll
                for (int t = 0; t < 9; ++t) {
                    int ky = t / 3, kx = t % 3;
                    bhalf8 bfr = *(const bhalf8*)
                        &hn[swz((row + ky)*32 + kx + nn + x0R, quad*8)];
                    acc = __builtin_amdgcn_mfma_f32_16x16x32_bf16(afrB[t], bfr, acc, 0, 0, 0);
                }
                if (mbB < IG) {
                    int slot = row*32 + x0R + nn;
                    *(unsigned*)&rt_[swz(slot, mbB)] =
                        bf2pack(bflo(xa)*rcpf(acc[0]+EPSV), bfhi(xa)*rcpf(acc[1]+EPSV));
                    *(unsigned*)&rt_[swz(slot, mbB + 2)] =
                        bf2pack(bflo(xc)*rcpf(acc[2]+EPSV), bfhi(xc)*rcpf(acc[3]+EPSV));
                }
            }
        }
    }
    __syncthreads();

    // ---- Phase C: forward conv + multiplicative update; 28 tasks (7r x 2xt x 2ot)
    {
        const ushort_t* ap = WfP + ((size_t)(g*9*2 + otB)*64 + lane)*8;
        bhalf8 afr[9];
        #pragma unroll
        for (int t = 0; t < 9; ++t) afr[t] = *(const bhalf8*)(ap + (size_t)t*2*64*8);
        int mb = mbB;

        #pragma unroll
        for (int i = 0; i < 4; ++i) {
            int tc = waveId + 8*i;       // 0..31, valid < 28; tc&1 == otB
            if (tc < 28) {
                int xt = (tc >> 1) & 1;
                int w  = tc >> 2;        // out row in band, 0..6
                int px0 = xt*12;
                floatx4 acc = (floatx4){0.f,0.f,0.f,0.f};
                #pragma unroll
                for (int t = 0; t < 9; ++t) {
                    int ky = t / 3, kx = t % 3;
                    bhalf8 bfr = *(const bhalf8*)
                        &rt_[swz((w + ky)*32 + kx + nn + px0, quad*8)];
                    acc = __builtin_amdgcn_mfma_f32_16x16x32_bf16(afr[t], bfr, acc, 0, 0, 0);
                }

                int grow = r0 + w;
                int pxh = px0 + nn;      // 0..27
                float psum = 0.f;
                if (mb < IG) {
                    unsigned off = (unsigned)(grow*WW + xb + pxh);
                    unsigned pb = planeBase + (unsigned)(mb >> 1);
                    uint2 hv = *(const uint2*)&hn[swz((w + 2)*32 + pxh + 2, mb)];
                    float h0 = bflo(hv.x) * acc[0];
                    float h1 = bfhi(hv.x) * acc[1];
                    float h2 = bflo(hv.y) * acc[2];
                    float h3 = bfhi(hv.y) * acc[3];
                    HupO[(size_t)pb*HWHW + off]     = bf2pack(h0, h1);
                    HupO[(size_t)(pb+1)*HWHW + off] = bf2pack(h2, h3);
                    psum = h0 + h1 + h2 + h3;
                }
                psum += __shfl_down(psum, 32, 64);
                psum += __shfl_down(psum, 16, 64);
                if (lane < 16) sacc[otB*196 + w*28 + pxh] = psum;
            }
        }
    }
    __syncthreads();
    if (tid < 196) {
        Snxt[(size_t)g*NPIX + n*HWHW + (r0 + tid/28)*WW + xb + (tid % 28)]
            = sacc[tid] + sacc[196 + tid];
    }
}

// ---------------------------------------------------------------------------
// Fused residual + LN2 + MLP: 16 tokens/block, 128 thr.
// LN phase: px = tid&15, cg = tid>>4 (12 channels each); v kept in LDS so
// out is written ONCE (residual + MLP output). XLN tile lives in LDS.
__global__ __launch_bounds__(128) void mlpres_kernel(
        const float* __restrict__ x, const unsigned* __restrict__ Hup,
        const float* __restrict__ S4,
        const float* __restrict__ lw, const float* __restrict__ lb,
        const ushort_t* __restrict__ w1P, const float* __restrict__ b1,
        const ushort_t* __restrict__ w2P, const float* __restrict__ b2,
        float* __restrict__ out) {
    __shared__ ushort_t lh[16*392];      // 12544 B
    __shared__ unsigned xln[16*52];      // 3328 B  (pair cols 0..47, pad 52)
    __shared__ float vt[96*18];          // 6912 B  (row pad 18 vs 16)
    __shared__ float redS[8*16], redSS[8*16];
    __shared__ float uArr[16], rsArr[16];
    int blk = blockIdx.x;                // 1568
    int tid = threadIdx.x;
    int p0  = blk * 16;
    int n   = p0 / HWHW;
    int hw0 = p0 % HWHW;

    // ---- LN phase
    {
        int px = tid & 15, cg = tid >> 4;    // cg 0..7 -> channels cg*12..+11
        int p  = p0 + px, hw = hw0 + px;
        float stot = S4[p] + S4[NPIX+p] + S4[2*NPIX+p] + S4[3*NPIX+p];
        float sinv = 1.f / (stot + EPSV);
        int g = cg >> 1;
        unsigned plane = (unsigned)(n*4 + g)*12 + (unsigned)((cg & 1)*6);
        size_t xbase = (size_t)n*CC_*HWHW + hw;
        float v[12];
        float s = 0.f, ss = 0.f;
        #pragma unroll
        for (int j = 0; j < 6; ++j) {
            int c = cg*12 + 2*j;
            unsigned hu = Hup[(size_t)(plane + j)*HWHW + hw];
            float v0 = x[xbase + (size_t)c*HWHW]     + bflo(hu) * sinv;
            float v1 = x[xbase + (size_t)(c+1)*HWHW] + bfhi(hu) * sinv;
            v[2*j] = v0; v[2*j+1] = v1;
            s += v0 + v1; ss += v0*v0 + v1*v1;
        }
        redS[cg*16 + px] = s; redSS[cg*16 + px] = ss;
        __syncthreads();
        if (tid < 16) {
            float S_ = 0.f, SS_ = 0.f;
            #pragma unroll
            for (int k = 0; k < 8; ++k) { S_ += redS[k*16 + tid]; SS_ += redSS[k*16 + tid]; }
            float u  = S_ * (1.f/CC_);
            float var = SS_ * (1.f/CC_) - u*u;
            uArr[tid] = u; rsArr[tid] = rsqrtf(var + 1e-5f);
        }
        __syncthreads();
        float u = uArr[px], rs = rsArr[px];
        #pragma unroll
        for (int j = 0; j < 6; ++j) {
            int c = cg*12 + 2*j;
            float a0 = (v[2*j]   - u)*rs*lw[c]   + lb[c];
            float a1 = (v[2*j+1] - u)*rs*lw[c+1] + lb[c+1];
            xln[px*52 + cg*6 + j] = bf2pack(a0, a1);
            vt[c*18 + px]     = v[2*j];
            vt[(c+1)*18 + px] = v[2*j+1];
        }
    }
    __syncthreads();

    // ---- MLP phase
    int wv  = tid >> 6, lane = tid & 63;
    int quad = lane >> 4, nn = lane & 15;

    bhalf8 a1[3];
    #pragma unroll
    for (int ks = 0; ks < 3; ++ks)
        a1[ks] = *(const bhalf8*)&xln[nn*52 + ks*16 + quad*4];

    #pragma unroll 1
    for (int i = 0; i < 12; ++i) {
        int nt = wv*12 + i;
        floatx4 acc = (floatx4){0.f,0.f,0.f,0.f};
        #pragma unroll
        for (int ks = 0; ks < 3; ++ks) {
            bhalf8 bfr = *(const bhalf8*)(w1P + ((size_t)(nt*3 + ks)*64 + lane)*8);
            acc = __builtin_amdgcn_mfma_f32_16x16x32_bf16(a1[ks], bfr, acc, 0, 0, 0);
        }
        float b1v = b1[nt*16 + nn];
        #pragma unroll
        for (int r = 0; r < 4; ++r) {
            float h = acc[r] + b1v;
            h = 0.5f * h * (1.f + erff(h * 0.70710678118654752440f));
            lh[(quad*4 + r)*392 + nt*16 + nn] = bf1pack(h);
        }
    }
    __syncthreads();

    bhalf8 bf2[12];
    #pragma unroll
    for (int ks = 0; ks < 12; ++ks)
        bf2[ks] = *(const bhalf8*)&lh[nn*392 + ks*32 + quad*8];

    #pragma unroll 1
    for (int i = 0; i < 3; ++i) {
        int mt = wv*3 + i;
        floatx4 acc = (floatx4){0.f,0.f,0.f,0.f};
        #pragma unroll
        for (int ks = 0; ks < 12; ++ks) {
            bhalf8 af = *(const bhalf8*)(w2P + ((size_t)(mt*12 + ks)*64 + lane)*8);
            acc = __builtin_amdgcn_mfma_f32_16x16x32_bf16(af, bf2[ks], acc, 0, 0, 0);
        }
        #pragma unroll
        for (int r = 0; r < 4; ++r) {
            int c = mt*16 + quad*4 + r;
            size_t addr = ((size_t)n*CC_ + c)*HWHW + hw0 + nn;
            out[addr] = vt[c*18 + nn] + (acc[r] + b2[c]);
        }
    }
}

// ---------------------------------------------------------------------------
extern "C" void kernel_launch(void* const* d_in, const int* in_sizes, int n_in,
                              void* d_out, int out_size, void* d_ws, size_t ws_size,
                              hipStream_t stream) {
    const float* x    = (const float*)d_in[0];
    const float* ln1w = (const float*)d_in[1];
    const float* ln1b = (const float*)d_in[2];
    const float* wnn  = (const float*)d_in[3];
    const float* ln2w = (const float*)d_in[4];
    const float* ln2b = (const float*)d_in[5];
    const float* w1   = (const float*)d_in[6];
    const float* b1   = (const float*)d_in[7];
    const float* w2   = (const float*)d_in[8];
    const float* b2   = (const float*)d_in[9];
    float* out = (float*)d_out;
    char* ws = (char*)d_ws;

    ushort_t* WfP  = (ushort_t*)ws;                   ws += 73728*2;
    ushort_t* WtP  = (ushort_t*)ws;                   ws += 73728*2;
    ushort_t* w1P  = (ushort_t*)ws;                   ws += 36864*2;
    ushort_t* w2P  = (ushort_t*)ws;                   ws += 36864*2;
    unsigned* Xp   = (unsigned*)ws;                   ws += (size_t)(NELEM/2)*4;
    unsigned* Hu0  = (unsigned*)ws;                   ws += (size_t)(NELEM/2)*4;
    unsigned* Hu1  = (unsigned*)ws;                   ws += (size_t)(NELEM/2)*4;
    float*    SA   = (float*)ws;                      ws += (size_t)4*NPIX*4;
    float*    SB   = (float*)ws;                      ws += (size_t)4*NPIX*4;

    // bf16(1/96) on host (RNE), and the matching per-group channel-sum init
    union { float f; unsigned u; } cv; cv.f = 1.f/96.f;
    unsigned ur = cv.u + 0x7fffu + ((cv.u >> 16) & 1u);
    unsigned short hbits = (unsigned short)(ur >> 16);
    unsigned huInit = ((unsigned)hbits << 16) | hbits;
    union { float f; unsigned u; } hv; hv.u = ((unsigned)hbits) << 16;
    float sInit = 24.f * hv.f;

    // One fused prep launch: wnorm+wpack, mlppack, ln1.
    prep_kernel<<<138, 256, 0, stream>>>(wnn, WfP, WtP, w1, w2, w1P, w2P,
                                         x, ln1w, ln1b, Xp);
    // it0 staging is constant-generated in-kernel: no Hu0/SA fills needed.

    for (int it = 0; it < NITER; ++it) {
        const unsigned* HuI  = (it & 1) ? Hu1 : Hu0;
        unsigned*       HuO  = (it & 1) ? Hu0 : Hu1;
        const float*    Scur = (it & 1) ? SB : SA;
        float*          Snxt = (it & 1) ? SA : SB;
        nnmf_mfma_kernel<<<512, 512, 0, stream>>>(HuI, HuO, Scur, Snxt, WtP, WfP, Xp,
                                                  (it == 0) ? 1 : 0, huInit, sInit);
    }
    // 25 iterations: final Hu in Hu1, final S in SB

    mlpres_kernel<<<NPIX/16, 128, 0, stream>>>(x, Hu1, SB, ln2w, ln2b,
                                               w1P, b1, w2P, b2, out);
}